// Round 2
// baseline (914.221 us; speedup 1.0000x reference)
//
#include <hip/hip_runtime.h>

typedef unsigned short u16;
typedef __bf16 bf16x8 __attribute__((ext_vector_type(8)));
typedef float f32x4 __attribute__((ext_vector_type(4)));

static __device__ __forceinline__ u16 f32_to_bf16(float f) {
    unsigned u = __builtin_bit_cast(unsigned, f);
    u += 0x7fffu + ((u >> 16) & 1u);   // RNE
    return (u16)(u >> 16);
}
static __device__ __forceinline__ float bf16_to_f32(u16 v) {
    return __builtin_bit_cast(float, ((unsigned)v) << 16);
}

// ---------------------------------------------------------------------------
// Cast fp32 -> bf16, vectorized (n multiple of 4)
// ---------------------------------------------------------------------------
__global__ __launch_bounds__(256) void cast_f32_bf16(const float* __restrict__ in,
                                                     u16* __restrict__ out, int n)
{
    int i = (blockIdx.x * 256 + threadIdx.x) * 4;
    if (i >= n) return;
    float4 v = *reinterpret_cast<const float4*>(in + i);
    ushort4 o;
    o.x = f32_to_bf16(v.x); o.y = f32_to_bf16(v.y);
    o.z = f32_to_bf16(v.z); o.w = f32_to_bf16(v.w);
    *reinterpret_cast<ushort4*>(out + i) = o;
}

// ---------------------------------------------------------------------------
// GEMM: C[M,N] = A[M,K] * B[N,K]^T   (both row-major, K contiguous), bf16 out
// 64x64 tile / block, 256 thr (4 waves), BK=32, wave w does rows w*16..w*16+16
// ---------------------------------------------------------------------------
__global__ __launch_bounds__(256) void gemm_abt_bf16(
    const u16* __restrict__ A, const u16* __restrict__ B,
    u16* __restrict__ C, int M, int N, int K)
{
    __shared__ __align__(16) u16 As[64][40];
    __shared__ __align__(16) u16 Bs[64][40];
    const int tid  = threadIdx.x;
    const int wave = tid >> 6, lane = tid & 63;
    const int quad = lane >> 4, l16 = lane & 15;
    const int m0 = blockIdx.y * 64, n0 = blockIdx.x * 64;

    f32x4 acc[4] = {};
    const int lr = tid >> 2;          // 0..63
    const int lc = (tid & 3) * 8;     // 0,8,16,24
    const u16* Ap = A + (size_t)(m0 + lr) * K + lc;
    const u16* Bp = B + (size_t)(n0 + lr) * K + lc;

    for (int k0 = 0; k0 < K; k0 += 32) {
        __syncthreads();
        *reinterpret_cast<int4*>(&As[lr][lc]) = *reinterpret_cast<const int4*>(Ap + k0);
        *reinterpret_cast<int4*>(&Bs[lr][lc]) = *reinterpret_cast<const int4*>(Bp + k0);
        __syncthreads();
        bf16x8 a = *reinterpret_cast<const bf16x8*>(&As[wave * 16 + l16][quad * 8]);
#pragma unroll
        for (int cb = 0; cb < 4; ++cb) {
            bf16x8 b = *reinterpret_cast<const bf16x8*>(&Bs[cb * 16 + l16][quad * 8]);
            acc[cb] = __builtin_amdgcn_mfma_f32_16x16x32_bf16(a, b, acc[cb], 0, 0, 0);
        }
    }
#pragma unroll
    for (int cb = 0; cb < 4; ++cb)
#pragma unroll
        for (int r = 0; r < 4; ++r) {
            int row = m0 + wave * 16 + quad * 4 + r;
            int col = n0 + cb * 16 + l16;
            C[(size_t)row * N + col] = f32_to_bf16(acc[cb][r]);
        }
}

// Same GEMM, + residual add from X (fp32), f32 output (for LayerNorm)
__global__ __launch_bounds__(256) void gemm_abt_res_f32(
    const u16* __restrict__ A, const u16* __restrict__ B,
    const float* __restrict__ X, float* __restrict__ C, int M, int N, int K)
{
    __shared__ __align__(16) u16 As[64][40];
    __shared__ __align__(16) u16 Bs[64][40];
    const int tid  = threadIdx.x;
    const int wave = tid >> 6, lane = tid & 63;
    const int quad = lane >> 4, l16 = lane & 15;
    const int m0 = blockIdx.y * 64, n0 = blockIdx.x * 64;

    f32x4 acc[4] = {};
    const int lr = tid >> 2;
    const int lc = (tid & 3) * 8;
    const u16* Ap = A + (size_t)(m0 + lr) * K + lc;
    const u16* Bp = B + (size_t)(n0 + lr) * K + lc;

    for (int k0 = 0; k0 < K; k0 += 32) {
        __syncthreads();
        *reinterpret_cast<int4*>(&As[lr][lc]) = *reinterpret_cast<const int4*>(Ap + k0);
        *reinterpret_cast<int4*>(&Bs[lr][lc]) = *reinterpret_cast<const int4*>(Bp + k0);
        __syncthreads();
        bf16x8 a = *reinterpret_cast<const bf16x8*>(&As[wave * 16 + l16][quad * 8]);
#pragma unroll
        for (int cb = 0; cb < 4; ++cb) {
            bf16x8 b = *reinterpret_cast<const bf16x8*>(&Bs[cb * 16 + l16][quad * 8]);
            acc[cb] = __builtin_amdgcn_mfma_f32_16x16x32_bf16(a, b, acc[cb], 0, 0, 0);
        }
    }
#pragma unroll
    for (int cb = 0; cb < 4; ++cb)
#pragma unroll
        for (int r = 0; r < 4; ++r) {
            int row = m0 + wave * 16 + quad * 4 + r;
            int col = n0 + cb * 16 + l16;
            C[(size_t)row * N + col] = acc[cb][r] + X[(size_t)row * N + col];
        }
}

// ---------------------------------------------------------------------------
// Attention: per block (qt, h, b): 64 Q rows. Two-phase online softmax.
// Q,K,V bf16 [B,S,HID]-strided per head; attn probs written fp32.
// ---------------------------------------------------------------------------
__global__ __launch_bounds__(256) void attn_kernel(
    const u16* __restrict__ Q, const u16* __restrict__ K,
    const u16* __restrict__ V, const int* __restrict__ mask,
    float* __restrict__ attn_out, u16* __restrict__ ctx_out)
{
    constexpr int S = 2048, HID = 1024, NH = 16;
    __shared__ __align__(16) u16 Qs[64][72];
    __shared__ __align__(16) u16 Ks[64][72];
    __shared__ __align__(16) u16 Vt[64][72];  // transposed: [d][k]
    __shared__ __align__(16) u16 Ps[64][72];

    const int tid  = threadIdx.x;
    const int wave = tid >> 6, lane = tid & 63;
    const int quad = lane >> 4, l16 = lane & 15;
    const int qt = blockIdx.x, h = blockIdx.y, b = blockIdx.z;
    const size_t qkv_base = (size_t)b * S * HID + h * 64;

    const int lr = tid >> 2;          // 0..63
    const int lc = (tid & 3) * 16;    // 0,16,32,48
    // load Q tile
    {
        const u16* p = Q + qkv_base + (size_t)(qt * 64 + lr) * HID + lc;
        *reinterpret_cast<int4*>(&Qs[lr][lc])     = *reinterpret_cast<const int4*>(p);
        *reinterpret_cast<int4*>(&Qs[lr][lc + 8]) = *reinterpret_cast<const int4*>(p + 8);
    }

    float m_i[4], l_i[4];
#pragma unroll
    for (int r = 0; r < 4; ++r) { m_i[r] = -1e30f; l_i[r] = 0.f; }

    const int q_row0 = qt * 64 + wave * 16 + quad * 4;  // + r
    const size_t mask_b = (size_t)b * S * S;

    // ---------------- phase 1: row max + sumexp ----------------
    for (int kt = 0; kt < S / 64; ++kt) {
        __syncthreads();
        {
            const u16* p = K + qkv_base + (size_t)(kt * 64 + lr) * HID + lc;
            *reinterpret_cast<int4*>(&Ks[lr][lc])     = *reinterpret_cast<const int4*>(p);
            *reinterpret_cast<int4*>(&Ks[lr][lc + 8]) = *reinterpret_cast<const int4*>(p + 8);
        }
        __syncthreads();
        f32x4 sc[4] = {};
#pragma unroll
        for (int ks = 0; ks < 2; ++ks) {
            bf16x8 a = *reinterpret_cast<const bf16x8*>(&Qs[wave * 16 + l16][ks * 32 + quad * 8]);
#pragma unroll
            for (int cb = 0; cb < 4; ++cb) {
                bf16x8 bb = *reinterpret_cast<const bf16x8*>(&Ks[cb * 16 + l16][ks * 32 + quad * 8]);
                sc[cb] = __builtin_amdgcn_mfma_f32_16x16x32_bf16(a, bb, sc[cb], 0, 0, 0);
            }
        }
        float s_val[4][4];
#pragma unroll
        for (int cb = 0; cb < 4; ++cb) {
            int kcol = kt * 64 + cb * 16 + l16;
#pragma unroll
            for (int r = 0; r < 4; ++r) {
                int q = q_row0 + r;
                int mv = mask[mask_b + (size_t)q * S + kcol];
                s_val[cb][r] = (mv == 0) ? -1e9f : sc[cb][r] * 0.125f;
            }
        }
#pragma unroll
        for (int r = 0; r < 4; ++r) {
            float mx = fmaxf(fmaxf(s_val[0][r], s_val[1][r]), fmaxf(s_val[2][r], s_val[3][r]));
            mx = fmaxf(mx, __shfl_xor(mx, 1));
            mx = fmaxf(mx, __shfl_xor(mx, 2));
            mx = fmaxf(mx, __shfl_xor(mx, 4));
            mx = fmaxf(mx, __shfl_xor(mx, 8));
            float m_new = fmaxf(m_i[r], mx);
            float sum = 0.f;
#pragma unroll
            for (int cb = 0; cb < 4; ++cb) sum += __expf(s_val[cb][r] - m_new);
            sum += __shfl_xor(sum, 1);
            sum += __shfl_xor(sum, 2);
            sum += __shfl_xor(sum, 4);
            sum += __shfl_xor(sum, 8);
            l_i[r] = l_i[r] * __expf(m_i[r] - m_new) + sum;
            m_i[r] = m_new;
        }
    }
    float rl[4];
#pragma unroll
    for (int r = 0; r < 4; ++r) rl[r] = 1.0f / l_i[r];

    // ---------------- phase 2: write attn + P*V ----------------
    f32x4 ctx[4] = {};
    for (int kt = 0; kt < S / 64; ++kt) {
        __syncthreads();
        {
            const u16* p = K + qkv_base + (size_t)(kt * 64 + lr) * HID + lc;
            *reinterpret_cast<int4*>(&Ks[lr][lc])     = *reinterpret_cast<const int4*>(p);
            *reinterpret_cast<int4*>(&Ks[lr][lc + 8]) = *reinterpret_cast<const int4*>(p + 8);
            const u16* pv = V + qkv_base + (size_t)(kt * 64 + lr) * HID + lc;
            union { int4 v; u16 s[8]; } b0, b1;
            b0.v = *reinterpret_cast<const int4*>(pv);
            b1.v = *reinterpret_cast<const int4*>(pv + 8);
#pragma unroll
            for (int j = 0; j < 8; ++j) Vt[lc + j][lr] = b0.s[j];
#pragma unroll
            for (int j = 0; j < 8; ++j) Vt[lc + 8 + j][lr] = b1.s[j];
        }
        __syncthreads();
        f32x4 sc[4] = {};
#pragma unroll
        for (int ks = 0; ks < 2; ++ks) {
            bf16x8 a = *reinterpret_cast<const bf16x8*>(&Qs[wave * 16 + l16][ks * 32 + quad * 8]);
#pragma unroll
            for (int cb = 0; cb < 4; ++cb) {
                bf16x8 bb = *reinterpret_cast<const bf16x8*>(&Ks[cb * 16 + l16][ks * 32 + quad * 8]);
                sc[cb] = __builtin_amdgcn_mfma_f32_16x16x32_bf16(a, bb, sc[cb], 0, 0, 0);
            }
        }
#pragma unroll
        for (int cb = 0; cb < 4; ++cb) {
            int kcol = kt * 64 + cb * 16 + l16;
#pragma unroll
            for (int r = 0; r < 4; ++r) {
                int q = q_row0 + r;
                int mv = mask[mask_b + (size_t)q * S + kcol];
                float s = (mv == 0) ? -1e9f : sc[cb][r] * 0.125f;
                float pval = __expf(s - m_i[r]) * rl[r];
                Ps[wave * 16 + quad * 4 + r][cb * 16 + l16] = f32_to_bf16(pval);
            }
        }
        __syncthreads();
        // coalesced fp32 attn write from LDS (bf16 -> f32 upconvert)
        {
            size_t arow = (((size_t)(b * NH + h) * S) + qt * 64 + lr) * S + kt * 64 + lc;
#pragma unroll
            for (int g = 0; g < 4; ++g) {
                float4 o;
                o.x = bf16_to_f32(Ps[lr][lc + g * 4 + 0]);
                o.y = bf16_to_f32(Ps[lr][lc + g * 4 + 1]);
                o.z = bf16_to_f32(Ps[lr][lc + g * 4 + 2]);
                o.w = bf16_to_f32(Ps[lr][lc + g * 4 + 3]);
                *reinterpret_cast<float4*>(&attn_out[arow + g * 4]) = o;
            }
        }
        // P @ V
#pragma unroll
        for (int ks = 0; ks < 2; ++ks) {
            bf16x8 a = *reinterpret_cast<const bf16x8*>(&Ps[wave * 16 + l16][ks * 32 + quad * 8]);
#pragma unroll
            for (int cb = 0; cb < 4; ++cb) {
                bf16x8 bb = *reinterpret_cast<const bf16x8*>(&Vt[cb * 16 + l16][ks * 32 + quad * 8]);
                ctx[cb] = __builtin_amdgcn_mfma_f32_16x16x32_bf16(a, bb, ctx[cb], 0, 0, 0);
            }
        }
    }
    // write context (bf16 workspace)
#pragma unroll
    for (int cb = 0; cb < 4; ++cb)
#pragma unroll
        for (int r = 0; r < 4; ++r) {
            int q = q_row0 + r;
            int d = cb * 16 + l16;
            ctx_out[qkv_base + (size_t)q * HID + d] = f32_to_bf16(ctx[cb][r]);
        }
}

// ---------------------------------------------------------------------------
// LayerNorm over last dim (1024), f32 in -> f32 out
// ---------------------------------------------------------------------------
__global__ __launch_bounds__(256) void ln_kernel(const float* __restrict__ X,
                                                 float* __restrict__ out)
{
    __shared__ float red[8];
    const int row = blockIdx.x;
    const int tid = threadIdx.x;
    const int wave = tid >> 6, lane = tid & 63;
    const float* xr = X + (size_t)row * 1024;
    float v[4];
    float s = 0.f;
#pragma unroll
    for (int i = 0; i < 4; ++i) { v[i] = xr[tid + 256 * i]; s += v[i]; }
#pragma unroll
    for (int off = 1; off < 64; off <<= 1) s += __shfl_xor(s, off);
    if (lane == 0) red[wave] = s;
    __syncthreads();
    float mean = (red[0] + red[1] + red[2] + red[3]) * (1.0f / 1024.0f);
    float s2 = 0.f;
#pragma unroll
    for (int i = 0; i < 4; ++i) { float d = v[i] - mean; s2 += d * d; }
#pragma unroll
    for (int off = 1; off < 64; off <<= 1) s2 += __shfl_xor(s2, off);
    if (lane == 0) red[4 + wave] = s2;
    __syncthreads();
    float var = (red[4] + red[5] + red[6] + red[7]) * (1.0f / 1024.0f);
    float rstd = rsqrtf(var + 1e-5f);
#pragma unroll
    for (int i = 0; i < 4; ++i)
        out[(size_t)row * 1024 + tid + 256 * i] = (v[i] - mean) * rstd;
}

// ---------------------------------------------------------------------------
extern "C" void kernel_launch(void* const* d_in, const int* in_sizes, int n_in,
                              void* d_out, int out_size, void* d_ws, size_t ws_size,
                              hipStream_t stream)
{
    constexpr int B = 2, S = 2048, HID = 1024, NH = 16;
    constexpr int M = B * S;  // 4096

    const float* X  = (const float*)d_in[0];
    const int* mask = (const int*)d_in[1];
    const float* WQ = (const float*)d_in[2];
    const float* WK = (const float*)d_in[3];
    const float* WV = (const float*)d_in[4];
    const float* WO = (const float*)d_in[5];

    float* out  = (float*)d_out;                    // [B,S,HID] fp32
    float* attn = out + (size_t)M * HID;            // [B,NH,S,S] fp32

    u16*   Xb  = (u16*)d_ws;                        // bf16 casts
    u16*   WQb = Xb  + (size_t)M * HID;
    u16*   WKb = WQb + (size_t)HID * HID;
    u16*   WVb = WKb + (size_t)HID * HID;
    u16*   WOb = WVb + (size_t)HID * HID;
    u16*   Qw  = WOb + (size_t)HID * HID;
    u16*   Kw  = Qw  + (size_t)M * HID;
    u16*   Vw  = Kw  + (size_t)M * HID;
    u16*   Cw  = Vw  + (size_t)M * HID;
    float* XO  = (float*)(Cw + (size_t)M * HID);

    dim3 blk(256);
    cast_f32_bf16<<<dim3((M * HID) / 1024), blk, 0, stream>>>(X,  Xb,  M * HID);
    cast_f32_bf16<<<dim3((HID * HID) / 1024), blk, 0, stream>>>(WQ, WQb, HID * HID);
    cast_f32_bf16<<<dim3((HID * HID) / 1024), blk, 0, stream>>>(WK, WKb, HID * HID);
    cast_f32_bf16<<<dim3((HID * HID) / 1024), blk, 0, stream>>>(WV, WVb, HID * HID);
    cast_f32_bf16<<<dim3((HID * HID) / 1024), blk, 0, stream>>>(WO, WOb, HID * HID);

    dim3 ggrid(HID / 64, M / 64);
    gemm_abt_bf16<<<ggrid, blk, 0, stream>>>(Xb, WQb, Qw, M, HID, HID);
    gemm_abt_bf16<<<ggrid, blk, 0, stream>>>(Xb, WKb, Kw, M, HID, HID);
    gemm_abt_bf16<<<ggrid, blk, 0, stream>>>(Xb, WVb, Vw, M, HID, HID);

    dim3 agrid(S / 64, NH, B);
    attn_kernel<<<agrid, blk, 0, stream>>>(Qw, Kw, Vw, mask, attn, Cw);

    gemm_abt_res_f32<<<ggrid, blk, 0, stream>>>(Cw, WOb, X, XO, M, HID, HID);
    ln_kernel<<<dim3(M), blk, 0, stream>>>(XO, out);
}